// Round 1
// 812.193 us; speedup vs baseline: 1.1902x; 1.1902x over previous
//
#include <hip/hip_runtime.h>
#include <cstdint>
#include <cstddef>

// Problem constants (from reference setup)
#define SEQ   2048
#define HID   1024
#define NBAT  64
#define NSEG  4
#define NNODE 7
#define TCHUNK 128   // tokens per pooling block chunk (SEQ/TCHUNK = 16 chunks)

__device__ __forceinline__ float gelu_f(float x) {
  // exact erf gelu (jax approximate=False / torch default GELU)
  return 0.5f * x * (1.0f + erff(x * 0.7071067811865476f));
}

// ---------------------------------------------------------------------------
// Kernel 1: ragged segment-sum pooling (unchanged — at HBM read floor).
// ---------------------------------------------------------------------------
__global__ __launch_bounds__(256) void pool_kernel(
    const float* __restrict__ states, const int* __restrict__ boundaries,
    const int* __restrict__ lengths, float* __restrict__ pooled_sum)
{
  const int tc = blockIdx.x, b = blockIdx.y;
  const int tid = threadIdx.x;
  const int len = lengths[b];
  int bnd[5];
  bnd[0] = boundaries[b * 4 + 0];
  bnd[1] = boundaries[b * 4 + 1];
  bnd[2] = boundaries[b * 4 + 2];
  bnd[3] = boundaries[b * 4 + 3];
  bnd[4] = len;
  const int clo = tc * TCHUNK, chi = clo + TCHUNK;
  const float4* S = (const float4*)(states + (size_t)b * SEQ * HID);

  #pragma unroll
  for (int s = 0; s < NSEG; ++s) {
    int lo = bnd[s]     > clo ? bnd[s]     : clo;
    int hi = bnd[s + 1] < chi ? bnd[s + 1] : chi;
    if (lo >= hi) continue;                       // block-uniform branch
    float4 acc = make_float4(0.f, 0.f, 0.f, 0.f);
    int t = lo;
    for (; t + 4 <= hi; t += 4) {
      float4 v0 = S[(size_t)(t + 0) * (HID / 4) + tid];
      float4 v1 = S[(size_t)(t + 1) * (HID / 4) + tid];
      float4 v2 = S[(size_t)(t + 2) * (HID / 4) + tid];
      float4 v3 = S[(size_t)(t + 3) * (HID / 4) + tid];
      acc.x += (v0.x + v1.x) + (v2.x + v3.x);
      acc.y += (v0.y + v1.y) + (v2.y + v3.y);
      acc.z += (v0.z + v1.z) + (v2.z + v3.z);
      acc.w += (v0.w + v1.w) + (v2.w + v3.w);
    }
    for (; t < hi; ++t) {
      float4 v = S[(size_t)t * (HID / 4) + tid];
      acc.x += v.x; acc.y += v.y; acc.z += v.z; acc.w += v.w;
    }
    float* dst = pooled_sum + (size_t)(b * NSEG + s) * HID + tid * 4;
    atomicAdd(dst + 0, acc.x);
    atomicAdd(dst + 1, acc.y);
    atomicAdd(dst + 2, acc.z);
    atomicAdd(dst + 3, acc.w);
  }
}

// ---------------------------------------------------------------------------
// Split-K fp32 tiled GEMM: Cp[z][M][1024] = A[M x Kslice(z)] @ W[Kslice(z) x 1024]
// Tile 32(M) x 64(N) x 32(K), 256 threads, 2x4 acc/thread, register prefetch.
// grid = (16, M/32, SPLIT) — chosen so every launch is exactly 256 blocks
// (1 block/CU) and the per-block serial K-loop is only K/SPLIT/32 = 4..16
// iterations (the GEMMs are latency-bound, not throughput-bound).
// AMODE 1: A = pooled_sum, rows scaled by 1/max(cnt,1)          (G1)
// AMODE 2: A = gather concat(node_repr[lc], node_repr[rc])      (G3, G5)
// AMODE 3: A[m][k] = gelu(sum_{z<SRCS} Apart[z][m][k] + biasA[k])
//          — fuses the previous stage's split-K reduction + bias + gelu
//          into this stage's LDS staging, for free.             (G2, G4, G6)
// Output is always a raw partial sum (bias/epilogue applied downstream).
// ---------------------------------------------------------------------------
#define BM 32
#define BN 64
#define BK 32

template<int AMODE, int SPLIT, int SRCS>
__global__ __launch_bounds__(256) void gemm_kernel(
    const float* __restrict__ A,       // AMODE1: pooled; AMODE3: partial base
    const float* __restrict__ W,
    const float* __restrict__ biasA,   // AMODE3: bias on A columns (pre-gelu)
    float* __restrict__ Cp,            // [SPLIT][M][1024] raw partials
    int M, int K,
    const int* __restrict__ boundaries, const int* __restrict__ lengths,
    const int* __restrict__ left_child, const int* __restrict__ right_child,
    const float* __restrict__ node_in, int nodeA, int nodeB)
{
  const int N = 1024;
  __shared__ float As[BK][BM + 2];   // padded, stride 34
  __shared__ float Ws[BK][BN];

  const int tid = threadIdx.x;
  const int n0 = blockIdx.x * BN;
  const int m0 = blockIdx.y * BM;
  const int z  = blockIdx.z;
  const int Kloc = K / SPLIT;
  const int kbeg = z * Kloc;

  const int am = tid >> 3;            // 0..31   A tile row (this thread stages)
  const int ak = (tid & 7) * 4;       // 0..28   A tile k
  const int wk = tid >> 3;            // 0..31   W tile k
  const int wn = (tid & 7) * 8;       // 0..56   W tile n
  const int rm = (tid >> 4) * 2;      // compute rows
  const int cn = (tid & 15) * 4;      // compute cols

  // Per-thread A addressing setup (hoisted out of the K-loop)
  float ainv = 1.0f;
  int lcn = 0, rcn = 0, arow_b = 0;
  if constexpr (AMODE == 1) {
    int m = m0 + am; int b = m >> 2; int s = m & 3;
    int bs = boundaries[b * 4 + s];
    int bn = (s < 3) ? boundaries[b * 4 + s + 1] : lengths[b];
    ainv = 1.0f / fmaxf((float)(bn - bs), 1.0f);
  } else if constexpr (AMODE == 2) {
    int mrow = m0 + am; int mi = mrow >> 6; int b = mrow & 63;
    int node = mi ? nodeB : nodeA;
    lcn = left_child[node]; rcn = right_child[node];
    arow_b = b;
  }

  float acc[2][4] = {{0.f,0.f,0.f,0.f},{0.f,0.f,0.f,0.f}};

  float4 av[SRCS]; float4 bv; float4 wv0, wv1;

  auto issueA = [&](int kcol) {
    if constexpr (AMODE == 3) {
      #pragma unroll
      for (int s = 0; s < SRCS; ++s)
        av[s] = *(const float4*)(A + ((size_t)s * M + (m0 + am)) * (size_t)K + kcol);
      bv = *(const float4*)(biasA + kcol);
    } else if constexpr (AMODE == 2) {
      int child = (kcol < 1024) ? lcn : rcn;
      av[0] = *(const float4*)(node_in + (size_t)(arow_b * NNODE + child) * 1024 + (kcol & 1023));
    } else {
      av[0] = *(const float4*)(A + (size_t)(m0 + am) * K + kcol);
    }
  };

  // ---- prefetch tile 0 into registers ----
  issueA(kbeg + ak);
  wv0 = *(const float4*)(W + (size_t)(kbeg + wk) * N + n0 + wn);
  wv1 = *(const float4*)(W + (size_t)(kbeg + wk) * N + n0 + wn + 4);

  for (int k0 = 0; k0 < Kloc; k0 += BK) {
    __syncthreads();                  // readers of previous tile done
    {
      float4 a;
      if constexpr (AMODE == 3) {
        float4 s = av[0];
        #pragma unroll
        for (int q = 1; q < SRCS; ++q) {
          s.x += av[q].x; s.y += av[q].y; s.z += av[q].z; s.w += av[q].w;
        }
        a.x = gelu_f(s.x + bv.x); a.y = gelu_f(s.y + bv.y);
        a.z = gelu_f(s.z + bv.z); a.w = gelu_f(s.w + bv.w);
      } else if constexpr (AMODE == 1) {
        a = av[0];
        a.x *= ainv; a.y *= ainv; a.z *= ainv; a.w *= ainv;
      } else {
        a = av[0];
      }
      As[ak + 0][am] = a.x;
      As[ak + 1][am] = a.y;
      As[ak + 2][am] = a.z;
      As[ak + 3][am] = a.w;
    }
    *(float4*)&Ws[wk][wn]     = wv0;
    *(float4*)&Ws[wk][wn + 4] = wv1;
    __syncthreads();                  // staging visible

    // issue next tile's loads NOW; waited at next iteration's store
    const int kn = k0 + BK;
    if (kn < Kloc) {
      issueA(kbeg + kn + ak);
      wv0 = *(const float4*)(W + (size_t)(kbeg + kn + wk) * N + n0 + wn);
      wv1 = *(const float4*)(W + (size_t)(kbeg + kn + wk) * N + n0 + wn + 4);
    }

    #pragma unroll
    for (int kk = 0; kk < BK; ++kk) {
      float2 a2 = *(const float2*)&As[kk][rm];
      float4 w  = *(const float4*)&Ws[kk][cn];
      acc[0][0] += a2.x * w.x; acc[0][1] += a2.x * w.y;
      acc[0][2] += a2.x * w.z; acc[0][3] += a2.x * w.w;
      acc[1][0] += a2.y * w.x; acc[1][1] += a2.y * w.y;
      acc[1][2] += a2.y * w.z; acc[1][3] += a2.y * w.w;
    }
  }

  // ---- write raw partial sums ----
  #pragma unroll
  for (int r = 0; r < 2; ++r) {
    const int m = m0 + rm + r;
    *(float4*)(Cp + ((size_t)z * M + m) * N + n0 + cn) =
        make_float4(acc[r][0], acc[r][1], acc[r][2], acc[r][3]);
  }
}

// ---------------------------------------------------------------------------
// Reduce split-K partials + bias, then apply the stage epilogue.
// grid = (M), 256 threads, one float4 per thread (1024 cols). µs-scale.
// EPI 1: leaf scatter   -> node_repr      (after G2)
// EPI 2: merge scatter  -> node_repr[1,2] (after G4)
// EPI 3: root + topology hash + shape_embed -> out (after G6)
// ---------------------------------------------------------------------------
template<int EPI, int SRCS>
__global__ __launch_bounds__(256) void redepi_kernel(
    const float* __restrict__ P, const float* __restrict__ bias, int M,
    const int* __restrict__ boundaries, const int* __restrict__ lengths,
    const int* __restrict__ leaf_order, const int* __restrict__ active,
    const int* __restrict__ is_leaf, const int* __restrict__ depth,
    const float* __restrict__ dembed, const float* __restrict__ sembed,
    float* __restrict__ node_out, int nodeA, int nodeB)
{
  const int m = blockIdx.x;
  const int n = threadIdx.x * 4;

  float4 x = *(const float4*)(P + (size_t)m * 1024 + n);
  #pragma unroll
  for (int q = 1; q < SRCS; ++q) {
    float4 p = *(const float4*)(P + ((size_t)q * M + m) * 1024 + n);
    x.x += p.x; x.y += p.y; x.z += p.z; x.w += p.w;
  }
  x.x += bias[n + 0]; x.y += bias[n + 1];
  x.z += bias[n + 2]; x.w += bias[n + 3];

  if constexpr (EPI == 1) {
    int b = m >> 2; int s = m & 3;
    int node  = leaf_order[b * 4 + s];
    int nclip = node < 0 ? 0 : node;
    int bs = boundaries[b * 4 + s];
    int bn = (s < 3) ? boundaries[b * 4 + s + 1] : lengths[b];
    bool ok = (node >= 0) && (is_leaf[b * NNODE + nclip] != 0) && (bn - bs > 0);
    int d = depth[nclip];
    const float* de = dembed + (size_t)d * 1024 + n;
    float sc = ok ? 1.0f : 0.0f;
    x.x = (x.x + de[0]) * sc; x.y = (x.y + de[1]) * sc;
    x.z = (x.z + de[2]) * sc; x.w = (x.w + de[3]) * sc;
    *(float4*)(node_out + (size_t)(b * NNODE + nclip) * 1024 + n) = x;
  } else if constexpr (EPI == 2) {
    int mi = m >> 6; int b = m & 63;
    int node = mi ? nodeB : nodeA;
    bool ii = (active[b * NNODE + node] != 0) && (is_leaf[b * NNODE + node] == 0);
    int d = depth[node];
    const float* de = dembed + (size_t)d * 1024 + n;
    float sc = ii ? 1.0f : 0.0f;
    x.x = (x.x + de[0]) * sc; x.y = (x.y + de[1]) * sc;
    x.z = (x.z + de[2]) * sc; x.w = (x.w + de[3]) * sc;
    *(float4*)(node_out + (size_t)(b * NNODE + node) * 1024 + n) = x;
  } else { // EPI == 3: root merge + topology hash + shape_embed -> out
    int b = m & 63;
    bool ii = (active[b * NNODE + 0] != 0) && (is_leaf[b * NNODE + 0] == 0);
    int d = depth[0];
    const float* de = dembed + (size_t)d * 1024 + n;
    float sc = ii ? 1.0f : 0.0f;
    long long h = 0, w = 1;
    #pragma unroll
    for (int i = 0; i < NNODE; ++i) {
      long long p = (long long)active[b * NNODE + i] * 2
                  + (long long)is_leaf[b * NNODE + i];
      h += p * w;
      w *= 31;
    }
    long long a = h < 0 ? -h : h;
    int sid = (int)(a % 256);
    const float* se = sembed + (size_t)sid * 1024 + n;
    x.x = (x.x + de[0]) * sc + se[0];
    x.y = (x.y + de[1]) * sc + se[1];
    x.z = (x.z + de[2]) * sc + se[2];
    x.w = (x.w + de[3]) * sc + se[3];
    *(float4*)(node_out + (size_t)b * 1024 + n) = x;
  }
}

// ---------------------------------------------------------------------------
extern "C" void kernel_launch(void* const* d_in, const int* in_sizes, int n_in,
                              void* d_out, int out_size, void* d_ws, size_t ws_size,
                              hipStream_t stream)
{
  const float* states     = (const float*)d_in[0];
  // d_in[1] (mask) is redundant: mask[b][t] == (t < lengths[b])
  const int* lengths      = (const int*)d_in[2];
  const int* boundaries   = (const int*)d_in[3];
  const int* leaf_order   = (const int*)d_in[4];
  const int* active       = (const int*)d_in[5];
  const int* is_leaf      = (const int*)d_in[6];
  const int* left_child   = (const int*)d_in[7];
  const int* right_child  = (const int*)d_in[8];
  const int* depth        = (const int*)d_in[9];
  const float* W1  = (const float*)d_in[10];
  const float* b1  = (const float*)d_in[11];
  const float* W2  = (const float*)d_in[12];
  const float* b2  = (const float*)d_in[13];
  const float* Wm1 = (const float*)d_in[14];
  const float* bm1 = (const float*)d_in[15];
  const float* Wm2 = (const float*)d_in[16];
  const float* bm2 = (const float*)d_in[17];
  const float* dembed = (const float*)d_in[18];
  const float* sembed = (const float*)d_in[19];
  float* out = (float*)d_out;

  // workspace layout (floats). Partials need no zero-init: every z-slice is
  // fully written by its split block before being read.
  float* pooled    = (float*)d_ws;               // 256*1024 (zero-init)
  float* P1 = pooled + 256 * 1024;               // 2*256*1024
  float* P2 = P1 + 2 * 256 * 1024;               // 2*256*1024
  float* P3 = P2 + 2 * 256 * 1024;               // 4*128*1024
  float* P4 = P3 + 4 * 128 * 1024;               // 4*128*1024
  float* P5 = P4 + 4 * 128 * 1024;               // 8*64*1024
  float* P6 = P5 + 8 * 64 * 1024;                // 8*64*1024
  float* node_repr = P6 + 8 * 64 * 1024;         // 7*64*1024

  hipMemsetAsync(pooled, 0, (size_t)256 * 1024 * sizeof(float), stream);

  // 1) pooling partial sums
  pool_kernel<<<dim3(SEQ / TCHUNK, NBAT), 256, 0, stream>>>(
      states, boundaries, lengths, pooled);

  // 2) P1[2] = (pooled/cnt) @ W1          M=256 K=1024, split-K=2 (256 blocks)
  gemm_kernel<1, 2, 1><<<dim3(16, 8, 2), 256, 0, stream>>>(
      pooled, W1, nullptr, P1, 256, 1024,
      boundaries, lengths, nullptr, nullptr, nullptr, -1, -1);

  // 3) P2[2] = gelu(sum P1 + b1) @ W2     M=256 K=1024, split-K=2
  gemm_kernel<3, 2, 2><<<dim3(16, 8, 2), 256, 0, stream>>>(
      P1, W2, b1, P2, 256, 1024,
      nullptr, nullptr, nullptr, nullptr, nullptr, -1, -1);

  //    leaves: node_repr = (sum P2 + b2 + dembed) * leaf_ok
  redepi_kernel<1, 2><<<dim3(256), 256, 0, stream>>>(
      P2, b2, 256, boundaries, lengths, leaf_order, active, is_leaf, depth,
      dembed, sembed, node_repr, -1, -1);

  // 4) level-1 merges (nodes 1, 2): P3[4] = concat @ Wm1   M=128 K=2048, split-K=4
  gemm_kernel<2, 4, 1><<<dim3(16, 4, 4), 256, 0, stream>>>(
      nullptr, Wm1, nullptr, P3, 128, 2048,
      nullptr, nullptr, left_child, right_child, node_repr, 1, 2);

  //    P4[4] = gelu(sum P3 + bm1) @ Wm2   M=128 K=1024, split-K=4
  gemm_kernel<3, 4, 4><<<dim3(16, 4, 4), 256, 0, stream>>>(
      P3, Wm2, bm1, P4, 128, 1024,
      nullptr, nullptr, nullptr, nullptr, nullptr, -1, -1);

  //    node_repr[1,2] = (sum P4 + bm2 + dembed) * is_int
  redepi_kernel<2, 4><<<dim3(128), 256, 0, stream>>>(
      P4, bm2, 128, boundaries, lengths, leaf_order, active, is_leaf, depth,
      dembed, sembed, node_repr, 1, 2);

  // 5) root merge (node 0): P5[8] = concat @ Wm1   M=64 K=2048, split-K=8
  gemm_kernel<2, 8, 1><<<dim3(16, 2, 8), 256, 0, stream>>>(
      nullptr, Wm1, nullptr, P5, 64, 2048,
      nullptr, nullptr, left_child, right_child, node_repr, 0, 0);

  //    P6[8] = gelu(sum P5 + bm1) @ Wm2   M=64 K=1024, split-K=8
  gemm_kernel<3, 8, 8><<<dim3(16, 2, 8), 256, 0, stream>>>(
      P5, Wm2, bm1, P6, 64, 1024,
      nullptr, nullptr, nullptr, nullptr, nullptr, -1, -1);

  //    out = (sum P6 + bm2 + dembed) * is_int + shape_embed[hash]
  redepi_kernel<3, 8><<<dim3(64), 256, 0, stream>>>(
      P6, bm2, 64, boundaries, lengths, leaf_order, active, is_leaf, depth,
      dembed, sembed, out, 0, 0);
}